// Round 1
// baseline (617.501 us; speedup 1.0000x reference)
//
#include <hip/hip_runtime.h>
#include <hip/hip_bf16.h>
#include <stdint.h>

// Problem constants (fixed by the reference): B=4, S=8192, IN=1024, OUT=1024
#define M_TOT  32768
#define K_DIM  1024
#define N_DIM  1024

typedef short bf16x8 __attribute__((ext_vector_type(8)));   // 8 bf16 = 4 VGPRs (guide §3)
typedef float f32x4  __attribute__((ext_vector_type(4)));

#define AS1(p) ((__attribute__((address_space(1))) void*)(p))
#define AS3(p) ((__attribute__((address_space(3))) void*)(p))

__device__ __forceinline__ uint32_t packbf2(float a, float b) {
    __hip_bfloat162 h = __float22bfloat162_rn(make_float2(a, b));
    union { __hip_bfloat162 h; uint32_t u; } cvt;
    cvt.h = h;
    return cvt.u;
}

// ---------- W fp32 -> bf16 (both matrices in one launch) ----------
__global__ __launch_bounds__(256) void wcvt_kernel(
        const float* __restrict__ wv, const float* __restrict__ wt,
        ushort* __restrict__ dv, ushort* __restrict__ dt) {
    int t = blockIdx.x * 256 + threadIdx.x;     // 0 .. 262143, 8 elems each
    const float* src; ushort* dst; int off;
    if (t < 131072) { src = wv; dst = dv; off = t * 8; }
    else            { src = wt; dst = dt; off = (t - 131072) * 8; }
    float4 a = *(const float4*)(src + off);
    float4 b = *(const float4*)(src + off + 4);
    uint4 p;
    p.x = packbf2(a.x, a.y);
    p.y = packbf2(a.z, a.w);
    p.z = packbf2(b.x, b.y);
    p.w = packbf2(b.z, b.w);
    *(uint4*)(dst + off) = p;
}

// ---------- mask compaction: visual rows -> V, text rows -> T ----------
// Order within each list is irrelevant (we scatter outputs by index).
__global__ __launch_bounds__(256) void compact_kernel(
        const int* __restrict__ mask, int* __restrict__ V, int* __restrict__ T,
        int* __restrict__ cnt) {
    int m = blockIdx.x * 256 + threadIdx.x;
    if (m >= M_TOT) return;
    if (mask[m] != 0) { int p = atomicAdd(cnt + 0, 1); V[p] = m; }
    else              { int p = atomicAdd(cnt + 1, 1); T[p] = m; }
}

// ---------- gathered-row 128x128 bf16 MFMA GEMM ----------
// Each block: 128 rows from one list (so ONE weight matrix), full K loop,
// 128 output cols.  A staged fp32->bf16 via VGPRs; B staged via
// global_load_lds width=16 with 16B-chunk XOR swizzle (conflict-free
// ds_read_b128 frag loads).  Epilogue scatters rows via the index list.
__global__ __launch_bounds__(256) void gemm_kernel(
        const float*  __restrict__ x,
        const ushort* __restrict__ Wv,
        const ushort* __restrict__ Wt,
        const int*    __restrict__ V,
        const int*    __restrict__ T,
        const int*    __restrict__ cnt,
        float*        __restrict__ out) {
    // chunk layout: chunk (row, kc) lives at LDS chunk index row*8 + (kc ^ (row&7))
    __shared__ ushort sA[128 * 64];   // 16 KB
    __shared__ ushort sB[128 * 64];   // 16 KB

    const int tid  = threadIdx.x;
    const int lane = tid & 63;
    const int w    = tid >> 6;

    // XCD-sticky swizzle: all 8 bn-blocks of one bm share blockIdx%8
    const int kx = blockIdx.x & 7;
    const int bn = (blockIdx.x >> 3) & 7;
    const int gk = blockIdx.x >> 6;
    const int bm = gk * 8 + kx;

    const int Nv  = cnt[0];
    const int Nt  = cnt[1];
    const int NBv = (Nv + 127) >> 7;
    const int NBt = (Nt + 127) >> 7;
    if (bm >= NBv + NBt) return;

    const bool vis = (bm < NBv);
    const int*    rowbase = vis ? (V + (size_t)bm * 128)
                                : (T + (size_t)(bm - NBv) * 128);
    const ushort* W       = vis ? Wv : Wt;
    const int n0 = bn * 128;

    // ---- staging assignment: thread covers chunks (m = i*32 + tid/8, kc = tid%8)
    const int kc = tid & 7;
    const int tr = tid >> 3;
    const float* xp[4];
    uint32_t aw[4];
#pragma unroll
    for (int i = 0; i < 4; ++i) {
        int m  = i * 32 + tr;
        int r  = rowbase[m];               // -1 = sentinel (padding row)
        int r4 = r < 0 ? 0 : r;            // safe address; store is masked later
        xp[i] = x + (size_t)r4 * K_DIM + kc * 8;
        aw[i] = (uint32_t)((m * 8 + (kc ^ (m & 7))) * 16);
    }
    // B DMA: LDS chunk p = r*256+tid must hold W row n=p>>3, chunk (p&7)^(n&7)
    const int kcb = (tid & 7) ^ (tr & 7);
    const ushort* wp[4];
#pragma unroll
    for (int r = 0; r < 4; ++r)
        wp[r] = W + (size_t)(n0 + r * 32 + tr) * K_DIM + kcb * 8;

    // ---- fragment read offsets (bytes) ----
    const int ml   = lane & 15;
    const int quad = lane >> 4;
    const int wm = (w & 1) * 64;
    const int wn = (w >> 1) * 64;
    uint32_t aoff[2][4], boff[2][4];
#pragma unroll
    for (int ks = 0; ks < 2; ++ks) {
        int kxr = (ks * 4 + quad) ^ (ml & 7);
#pragma unroll
        for (int t = 0; t < 4; ++t) {
            aoff[ks][t] = (uint32_t)(((wm + t * 16 + ml) * 8 + kxr) * 16);
            boff[ks][t] = (uint32_t)(((wn + t * 16 + ml) * 8 + kxr) * 16);
        }
    }

    f32x4 acc[4][4];
#pragma unroll
    for (int i = 0; i < 4; ++i)
#pragma unroll
        for (int j = 0; j < 4; ++j) {
            f32x4 z = {0.f, 0.f, 0.f, 0.f};
            acc[i][j] = z;
        }

    char* sAb = (char*)sA;
    char* sBb = (char*)sB;

    for (int kt = 0; kt < 16; ++kt) {
        const int k0 = kt * 64;
        // B tile: async global->LDS (issue first so DMA overlaps A round-trip)
#pragma unroll
        for (int r = 0; r < 4; ++r) {
            const ushort* g = wp[r] + k0;
            char* l = sBb + (size_t)(r * 256 + w * 64) * 16;  // wave-uniform base
            __builtin_amdgcn_global_load_lds(AS1(g), AS3(l), 16, 0, 0);
        }
        // A tile: gathered fp32 load -> bf16 pack -> LDS
#pragma unroll
        for (int i = 0; i < 4; ++i) {
            float4 a = *(const float4*)(xp[i] + k0);
            float4 b = *(const float4*)(xp[i] + k0 + 4);
            uint4 p;
            p.x = packbf2(a.x, a.y);
            p.y = packbf2(a.z, a.w);
            p.z = packbf2(b.x, b.y);
            p.w = packbf2(b.z, b.w);
            *(uint4*)(sAb + aw[i]) = p;
        }
        __syncthreads();   // drains vmcnt (DMA) + lgkmcnt before frag reads
#pragma unroll
        for (int ks = 0; ks < 2; ++ks) {
            bf16x8 af[4], bf[4];
#pragma unroll
            for (int t = 0; t < 4; ++t) af[t] = *(const bf16x8*)(sAb + aoff[ks][t]);
#pragma unroll
            for (int t = 0; t < 4; ++t) bf[t] = *(const bf16x8*)(sBb + boff[ks][t]);
#pragma unroll
            for (int tm = 0; tm < 4; ++tm)
#pragma unroll
                for (int tn = 0; tn < 4; ++tn)
                    acc[tm][tn] = __builtin_amdgcn_mfma_f32_16x16x32_bf16(
                        af[tm], bf[tn], acc[tm][tn], 0, 0, 0);
        }
        __syncthreads();
    }

    // ---- epilogue: scatter rows via index list (C/D: col=lane&15, row=quad*4+reg)
#pragma unroll
    for (int tm = 0; tm < 4; ++tm) {
        const int rb = wm + tm * 16 + quad * 4;
        int sr0 = rowbase[rb + 0];
        int sr1 = rowbase[rb + 1];
        int sr2 = rowbase[rb + 2];
        int sr3 = rowbase[rb + 3];
#pragma unroll
        for (int tn = 0; tn < 4; ++tn) {
            const int col = n0 + wn + tn * 16 + ml;
            if (sr0 >= 0) out[(size_t)sr0 * N_DIM + col] = acc[tm][tn][0];
            if (sr1 >= 0) out[(size_t)sr1 * N_DIM + col] = acc[tm][tn][1];
            if (sr2 >= 0) out[(size_t)sr2 * N_DIM + col] = acc[tm][tn][2];
            if (sr3 >= 0) out[(size_t)sr3 * N_DIM + col] = acc[tm][tn][3];
        }
    }
}

// ws layout:
//   [0, 2MB)        W_v bf16
//   [2MB, 4MB)      W_t bf16
//   [4MB, +128KB)   V index list (32768 int, -1 filled)
//   [.. , +128KB)   T index list (32768 int, -1 filled)
//   [.. , +8B)      counters {Nv, Nt}
extern "C" void kernel_launch(void* const* d_in, const int* in_sizes, int n_in,
                              void* d_out, int out_size, void* d_ws, size_t ws_size,
                              hipStream_t stream) {
    const float* x    = (const float*)d_in[0];
    const int*   mask = (const int*)d_in[1];
    const float* Wv   = (const float*)d_in[2];
    const float* Wt   = (const float*)d_in[3];
    float* out = (float*)d_out;

    char* ws = (char*)d_ws;
    ushort* dWv = (ushort*)(ws);
    ushort* dWt = (ushort*)(ws + 2097152);
    int* V   = (int*)(ws + 4194304);
    int* T   = V + 32768;
    int* cnt = T + 32768;

    hipMemsetAsync(V, 0xFF, 2 * 32768 * sizeof(int), stream);  // -1 sentinels
    hipMemsetAsync(cnt, 0, 2 * sizeof(int), stream);

    wcvt_kernel<<<1024, 256, 0, stream>>>(Wv, Wt, dWv, dWt);
    compact_kernel<<<M_TOT / 256, 256, 0, stream>>>(mask, V, T, cnt);
    // grid: bm = gk*8 + (blockIdx&7) must reach 256 -> gk up to 32 -> 33*64 blocks
    gemm_kernel<<<33 * 64, 256, 0, stream>>>(x, dWv, dWt, V, T, cnt, out);
}

// Round 2
// 352.579 us; speedup vs baseline: 1.7514x; 1.7514x over previous
//
#include <hip/hip_runtime.h>
#include <hip/hip_bf16.h>
#include <stdint.h>

// Problem constants (fixed by the reference): B=4, S=8192, IN=1024, OUT=1024
#define M_TOT  32768
#define K_DIM  1024
#define N_DIM  1024

typedef short bf16x8 __attribute__((ext_vector_type(8)));   // 8 bf16 = 4 VGPRs
typedef float f32x4  __attribute__((ext_vector_type(4)));

#define AS1(p) ((__attribute__((address_space(1))) void*)(p))
#define AS3(p) ((__attribute__((address_space(3))) void*)(p))

__device__ __forceinline__ uint32_t packbf2(float a, float b) {
    __hip_bfloat162 h = __float22bfloat162_rn(make_float2(a, b));
    union { __hip_bfloat162 h; uint32_t u; } cvt;
    cvt.h = h;
    return cvt.u;
}

// ---------- fp32 -> bf16: x (32M elems) + W_v + W_t (2M elems) in one pass ----------
__global__ __launch_bounds__(256) void cvt_kernel(
        const float* __restrict__ x,  const float* __restrict__ wv,
        const float* __restrict__ wt, ushort* __restrict__ xb,
        ushort* __restrict__ dv,      ushort* __restrict__ dt) {
    int t = blockIdx.x * 256 + threadIdx.x;         // 17408 blocks -> 4456448 threads
    const float* src; ushort* dst; int off;
    if (t < 4194304)      { src = x;  dst = xb; off = t * 8; }
    else {
        int u = t - 4194304;
        if (u < 131072)   { src = wv; dst = dv; off = u * 8; }
        else              { src = wt; dst = dt; off = (u - 131072) * 8; }
    }
    float4 a = *(const float4*)(src + off);
    float4 b = *(const float4*)(src + off + 4);
    uint4 p;
    p.x = packbf2(a.x, a.y);
    p.y = packbf2(a.z, a.w);
    p.z = packbf2(b.x, b.y);
    p.w = packbf2(b.z, b.w);
    *(uint4*)(dst + off) = p;
}

// ---------- deterministic single-block compaction (NO atomics) ----------
// 1024 threads x 32 contiguous elements each -> bitmask + popcount + scan.
// Produces SORTED V/T lists, counts, and -1 sentinels in the padding tail.
__global__ __launch_bounds__(1024) void compact_kernel(
        const int* __restrict__ mask, int* __restrict__ V, int* __restrict__ T,
        int* __restrict__ cnt) {
    const int tid  = threadIdx.x;
    const int lane = tid & 63;
    const int wv   = tid >> 6;

    // pass 1: 32 mask values -> bitmask
    const int4* mp = (const int4*)mask + tid * 8;
    uint32_t bits = 0;
#pragma unroll
    for (int i = 0; i < 8; ++i) {
        int4 v = mp[i];
        bits |= (uint32_t)(v.x != 0) << (i * 4 + 0);
        bits |= (uint32_t)(v.y != 0) << (i * 4 + 1);
        bits |= (uint32_t)(v.z != 0) << (i * 4 + 2);
        bits |= (uint32_t)(v.w != 0) << (i * 4 + 3);
    }
    int vcnt = __popc(bits);

    // wave-inclusive scan of vcnt
    int incl = vcnt;
#pragma unroll
    for (int d = 1; d < 64; d <<= 1) {
        int y = __shfl_up(incl, d);
        if (lane >= d) incl += y;
    }
    __shared__ int wsum[16], wexcl[16], totv_s;
    if (lane == 63) wsum[wv] = incl;
    __syncthreads();
    if (tid == 0) {
        int s = 0;
#pragma unroll
        for (int i = 0; i < 16; ++i) { wexcl[i] = s; s += wsum[i]; }
        totv_s = s;
    }
    __syncthreads();
    const int vexcl = wexcl[wv] + incl - vcnt;   // exclusive prefix of vcnt
    int vbase = vexcl;
    int tbase = tid * 32 - vexcl;                // text elems before my range

    // pass 2: write indices (disjoint positions, deterministic, sorted)
#pragma unroll
    for (int j = 0; j < 32; ++j) {
        int e = tid * 32 + j;
        if ((bits >> j) & 1u) V[vbase++] = e;
        else                  T[tbase++] = e;
    }

    const int Nv = totv_s, Nt = M_TOT - totv_s;
    if (tid == 0) { cnt[0] = Nv; cnt[1] = Nt; }

    // sentinel padding for the last partial 128-row tile of each list
    __syncthreads();
    const int NBv = (Nv + 127) >> 7, NBt = (Nt + 127) >> 7;
    for (int p = Nv + tid; p < NBv * 128; p += 1024) V[p] = -1;
    for (int p = Nt + tid; p < NBt * 128; p += 1024) T[p] = -1;
}

// ---------- gathered-row 128x128x(BK=64) bf16 MFMA GEMM, all-DMA staging ----------
// Each block: 128 rows from one list (ONE weight matrix), full K, 128 cols.
// A and B both staged via global_load_lds width=16 (gather is on the per-lane
// global address; LDS side is uniform base + lane*16).  16B-chunk XOR swizzle.
__global__ __launch_bounds__(256) void gemm_kernel(
        const ushort* __restrict__ xb,
        const ushort* __restrict__ Wv,
        const ushort* __restrict__ Wt,
        const int*    __restrict__ V,
        const int*    __restrict__ T,
        const int*    __restrict__ cnt,
        float*        __restrict__ out) {
    // chunk layout: chunk (row, kc) lives at LDS chunk index row*8 + (kc ^ (row&7))
    __shared__ ushort sA[128 * 64];   // 16 KB
    __shared__ ushort sB[128 * 64];   // 16 KB

    const int tid  = threadIdx.x;
    const int lane = tid & 63;
    const int w    = tid >> 6;

    // XCD-sticky swizzle: all 8 bn-blocks of one bm share blockIdx%8
    const int kx = blockIdx.x & 7;
    const int bn = (blockIdx.x >> 3) & 7;
    const int gk = blockIdx.x >> 6;
    const int bm = gk * 8 + kx;

    const int Nv  = cnt[0];
    const int Nt  = cnt[1];
    const int NBv = (Nv + 127) >> 7;
    const int NBt = (Nt + 127) >> 7;
    if (bm >= NBv + NBt) return;

    const bool vis = (bm < NBv);
    const int*    rowbase = vis ? (V + (size_t)bm * 128)
                                : (T + (size_t)(bm - NBv) * 128);
    const ushort* W       = vis ? Wv : Wt;
    const int n0 = bn * 128;

    // DMA source pointers: lane covers LDS chunk p = r*256+tid ->
    //   row n = r*32 + (tid>>3), chunk kc = (tid&7) ^ (n&7) = (tid&7)^((tid>>3)&7)
    const int trow = tid >> 3;
    const int kcb  = (tid & 7) ^ (trow & 7);
    const ushort* ap[4];
    const ushort* wp[4];
#pragma unroll
    for (int r = 0; r < 4; ++r) {
        int rr = rowbase[r * 32 + trow];
        if (rr < 0) rr = 0;                      // sentinel row: safe addr, masked at store
        ap[r] = xb + (size_t)rr * K_DIM + kcb * 8;
        wp[r] = W + (size_t)(n0 + r * 32 + trow) * K_DIM + kcb * 8;
    }

    // fragment read offsets (bytes)
    const int ml   = lane & 15;
    const int quad = lane >> 4;
    const int wm = (w & 1) * 64;
    const int wn = (w >> 1) * 64;
    uint32_t aoff[2][4], boff[2][4];
#pragma unroll
    for (int ks = 0; ks < 2; ++ks) {
        int kxr = (ks * 4 + quad) ^ (ml & 7);
#pragma unroll
        for (int t = 0; t < 4; ++t) {
            aoff[ks][t] = (uint32_t)(((wm + t * 16 + ml) * 8 + kxr) * 16);
            boff[ks][t] = (uint32_t)(((wn + t * 16 + ml) * 8 + kxr) * 16);
        }
    }

    f32x4 acc[4][4];
#pragma unroll
    for (int i = 0; i < 4; ++i)
#pragma unroll
        for (int j = 0; j < 4; ++j) {
            f32x4 z = {0.f, 0.f, 0.f, 0.f};
            acc[i][j] = z;
        }

    char* sAb = (char*)sA;
    char* sBb = (char*)sB;

    for (int kt = 0; kt < 16; ++kt) {
        const int k0 = kt * 64;
#pragma unroll
        for (int r = 0; r < 4; ++r) {
            char* lb = sBb + (size_t)(r * 256 + w * 64) * 16;   // wave-uniform base
            __builtin_amdgcn_global_load_lds(AS1(wp[r] + k0), AS3(lb), 16, 0, 0);
        }
#pragma unroll
        for (int r = 0; r < 4; ++r) {
            char* la = sAb + (size_t)(r * 256 + w * 64) * 16;
            __builtin_amdgcn_global_load_lds(AS1(ap[r] + k0), AS3(la), 16, 0, 0);
        }
        __syncthreads();   // drains vmcnt (DMA) before frag reads
#pragma unroll
        for (int ks = 0; ks < 2; ++ks) {
            bf16x8 af[4], bf[4];
#pragma unroll
            for (int t = 0; t < 4; ++t) af[t] = *(const bf16x8*)(sAb + aoff[ks][t]);
#pragma unroll
            for (int t = 0; t < 4; ++t) bf[t] = *(const bf16x8*)(sBb + boff[ks][t]);
#pragma unroll
            for (int tm = 0; tm < 4; ++tm)
#pragma unroll
                for (int tn = 0; tn < 4; ++tn)
                    acc[tm][tn] = __builtin_amdgcn_mfma_f32_16x16x32_bf16(
                        af[tm], bf[tn], acc[tm][tn], 0, 0, 0);
        }
        __syncthreads();
    }

    // epilogue: scatter rows via index list (C/D: col=lane&15, row=quad*4+reg)
    // lists are sorted -> stores are near-coalesced
#pragma unroll
    for (int tm = 0; tm < 4; ++tm) {
        const int rb = wm + tm * 16 + quad * 4;
        int sr0 = rowbase[rb + 0];
        int sr1 = rowbase[rb + 1];
        int sr2 = rowbase[rb + 2];
        int sr3 = rowbase[rb + 3];
#pragma unroll
        for (int tn = 0; tn < 4; ++tn) {
            const int col = n0 + wn + tn * 16 + ml;
            if (sr0 >= 0) out[(size_t)sr0 * N_DIM + col] = acc[tm][tn][0];
            if (sr1 >= 0) out[(size_t)sr1 * N_DIM + col] = acc[tm][tn][1];
            if (sr2 >= 0) out[(size_t)sr2 * N_DIM + col] = acc[tm][tn][2];
            if (sr3 >= 0) out[(size_t)sr3 * N_DIM + col] = acc[tm][tn][3];
        }
    }
}

// ws layout:
//   [0, 64MB)          x bf16 (32768 x 1024)
//   [64MB, 66MB)       W_v bf16
//   [66MB, 68MB)       W_t bf16
//   [68MB, +128KB)     V index list (32768 int)
//   [..,   +128KB)     T index list (32768 int)
//   [..,   +8B)        counters {Nv, Nt}
extern "C" void kernel_launch(void* const* d_in, const int* in_sizes, int n_in,
                              void* d_out, int out_size, void* d_ws, size_t ws_size,
                              hipStream_t stream) {
    const float* x    = (const float*)d_in[0];
    const int*   mask = (const int*)d_in[1];
    const float* Wv   = (const float*)d_in[2];
    const float* Wt   = (const float*)d_in[3];
    float* out = (float*)d_out;

    char* ws = (char*)d_ws;
    ushort* xb  = (ushort*)(ws);
    ushort* dWv = (ushort*)(ws + 67108864);
    ushort* dWt = (ushort*)(ws + 69206016);
    int* V   = (int*)(ws + 71303168);
    int* T   = V + 32768;
    int* cnt = T + 32768;

    cvt_kernel<<<17408, 256, 0, stream>>>(x, Wv, Wt, xb, dWv, dWt);
    compact_kernel<<<1, 1024, 0, stream>>>(mask, V, T, cnt);
    // grid: bm = gk*8 + (blockIdx&7) must reach ~258 -> gk up to 32 -> 33*64 blocks
    gemm_kernel<<<33 * 64, 256, 0, stream>>>(xb, dWv, dWt, V, T, cnt, out);
}